// Round 6
// baseline (501.463 us; speedup 1.0000x reference)
//
#include <hip/hip_runtime.h>

#define HW 3136
#define NPOS 12845056   // 16*256*3136

__device__ __forceinline__ unsigned fkey(float f) {
  unsigned u = __float_as_uint(f);
  return (u & 0x80000000u) ? ~u : (u | 0x80000000u);
}
__device__ __forceinline__ float funkey(unsigned u) {
  return __uint_as_float((u & 0x80000000u) ? (u & 0x7FFFFFFFu) : ~u);
}
__device__ __forceinline__ float spikef(float x) {
  return fminf(fmaxf(rintf(x), 0.0f), 4.0f);
}

// ---------------- Kernel 1: transposes + audio pre-projection + init ----------------
// grid 177 blocks x 256
__global__ __launch_bounds__(256) void prep_kernel(
    const float* __restrict__ audio, const float* __restrict__ w1,
    const float* __restrict__ b1, const float* __restrict__ w2,
    float* __restrict__ a_pre, float* __restrict__ w1t,
    float* __restrict__ w2t, float* __restrict__ pool,
    unsigned* __restrict__ mm)
{
  __shared__ float au[256];
  const int bx = blockIdx.x, t = threadIdx.x;
  if (bx < 128) {                       // w1 visual half -> w1t[c][j], coalesced write
    int idx = bx * 256 + t;             // 32768
    int c = idx >> 7, j = idx & 127;
    w1t[idx] = w1[j * 512 + c];
  } else if (bx < 160) {                // w2 -> w2t[k][j2], coalesced write
    int idx = (bx - 128) * 256 + t;     // 8192
    int k = idx >> 6, j2 = idx & 63;
    w2t[idx] = w2[j2 * 128 + k];
  } else if (bx < 176) {                // a_pre[b][j] = b1[j] + w1[j][256:512].audio[b]
    int b = bx - 160;
    au[t] = audio[b * 256 + t];
    __syncthreads();
    int w = t >> 6, l = t & 63;
    float a0 = au[l], a1 = au[l + 64], a2 = au[l + 128], a3 = au[l + 192];
    for (int jj = 0; jj < 32; ++jj) {
      int j = w * 32 + jj;
      const float* row = w1 + j * 512 + 256;
      float s = row[l] * a0 + row[l + 64] * a1 + row[l + 128] * a2 + row[l + 192] * a3;
      #pragma unroll
      for (int off = 32; off; off >>= 1) s += __shfl_xor(s, off);
      if (l == 0) a_pre[b * 128 + j] = s + b1[j];
    }
  } else {                              // init pool + minmax keys
    for (int i = t; i < 4096; i += 256) pool[i] = 0.0f;
    if (t == 0) { mm[0] = 0xFFFFFFFFu; mm[1] = 0u; }
  }
}

// ---------------- Kernel 2: fused MLP + mi + pooling ----------------
// 256 threads = 4 waves; 64 positions/block (1 per lane); wave = j-quarter.
// fm staged to LDS via global_load_lds (width=16, zero VGPR cost), double-
// buffered 64-channel chunks -> only 4 barriers in GEMM1, each covering
// 4096 cyc of FMA vs ~700 cyc load latency. Weights via wave-uniform scalar
// loads (SGPR FMA operand). grid 784 = 3.06 blocks/CU so barrier stalls in
// one block overlap compute in others. launch_bounds(256,3): VGPR cap ~170
// so acc[32] stays in arch VGPRs (round-5 AGPR-spill fix).
__global__ __launch_bounds__(256, 3) void mlp_kernel(
    const float* __restrict__ fm, const float* __restrict__ w1t,
    const float* __restrict__ w2t, const float* __restrict__ b2,
    const float* __restrict__ w3, const float* __restrict__ b3,
    const float* __restrict__ g1, const float* __restrict__ be1,
    const float* __restrict__ g2, const float* __restrict__ be2,
    const float* __restrict__ a_pre, float* __restrict__ mi_out,
    float* __restrict__ pool, unsigned* __restrict__ mm)
{
  __shared__ float fmbuf[2][64 * 64];    // 32 KB: double-buffered fm chunk [c][pos]
  __shared__ unsigned pk[32 * 64];       // h1 spikes packed 4-per-u32: 8 KB
  __shared__ float red1[4][64];
  __shared__ float red2[4][64];
  __shared__ float miL[64];

  const int b  = blockIdx.y;
  const int s0 = blockIdx.x * 64;
  const int t  = threadIdx.x;
  const int l  = t & 63;
  const int w  = __builtin_amdgcn_readfirstlane(t >> 6);

  const float* fmblk = fm + (size_t)b * 256 * HW + s0;
  const float* fmp   = fmblk + l;

  // stage 64-channel chunk ch into fmbuf[bufid]; each wave moves 16 channels
  // (4 rounds x 4 channels); LDS dst = uniform base + lane*16B (HW constraint)
  auto issue_chunk = [&](int ch, int bufid) {
    #pragma unroll
    for (int r = 0; r < 4; ++r) {
      int crel = r * 16 + w * 4 + (l >> 4);                  // 0..63 within chunk
      const float* gsrc = fmblk + (size_t)(ch * 64 + crel) * HW + (l & 15) * 4;
      float* ldst = &fmbuf[bufid][(r * 16 + w * 4) * 64];    // wave-uniform base
      __builtin_amdgcn_global_load_lds(
          (const __attribute__((address_space(1))) void*)gsrc,
          (__attribute__((address_space(3))) void*)ldst, 16, 0, 0);
    }
  };

  // ---- GEMM1: acc[32] = j-quarter, all 256 channels ----
  float acc[32];
  #pragma unroll
  for (int j = 0; j < 32; ++j) acc[j] = 0.f;

  const float* wq = w1t + w * 32;        // uniform -> scalar loads

  issue_chunk(0, 0);
  #pragma unroll 1
  for (int ch = 0; ch < 4; ++ch) {
    __syncthreads();                     // chunk ch resident in fmbuf[ch&1]
    if (ch < 3) issue_chunk(ch + 1, (ch + 1) & 1);
    const float* buf = fmbuf[ch & 1];
    #pragma unroll 8
    for (int cl = 0; cl < 64; ++cl) {
      const float* wr = wq + (ch * 64 + cl) * 128;  // 32 floats -> 2x s_load_dwordx16
      float x = buf[cl * 64 + l];                   // stride-1: conflict-free
      #pragma unroll
      for (int j = 0; j < 32; ++j) acc[j] = fmaf(x, wr[j], acc[j]);
    }
  }
  {
    const float* ap = a_pre + b * 128 + w * 32;     // uniform broadcast
    #pragma unroll
    for (int j = 0; j < 32; ++j) acc[j] += ap[j];
  }

  // ---- LN1 (two-pass) + spike + pack ----
  {
    float s = 0.f;
    #pragma unroll
    for (int j = 0; j < 32; ++j) s += acc[j];
    red1[w][l] = s;
  }
  __syncthreads();
  float mu = (red1[0][l] + red1[1][l] + red1[2][l] + red1[3][l]) * (1.0f / 128.0f);
  {
    float v = 0.f;
    #pragma unroll
    for (int j = 0; j < 32; ++j) { float d = acc[j] - mu; v = fmaf(d, d, v); }
    red2[w][l] = v;
  }
  __syncthreads();
  float var = (red2[0][l] + red2[1][l] + red2[2][l] + red2[3][l]) * (1.0f / 128.0f);
  float inv = 1.0f / sqrtf(var + 1e-5f);
  {
    const float* g1q  = g1  + w * 32;
    const float* be1q = be1 + w * 32;
    #pragma unroll
    for (int q = 0; q < 8; ++q) {
      unsigned u = 0;
      #pragma unroll
      for (int bb = 0; bb < 4; ++bb) {
        int j = q * 4 + bb;
        float v = spikef((acc[j] - mu) * inv * g1q[j] + be1q[j]);
        u |= ((unsigned)v) << (8 * bb);
      }
      pk[(w * 8 + q) * 64 + l] = u;     // lane-stride-1: conflict-free
    }
  }
  __syncthreads();

  // ---- GEMM2: acc2[16] = j-quarter of 64, full k=128 from packed LDS ----
  float acc2[16];
  #pragma unroll
  for (int j = 0; j < 16; ++j) acc2[j] = 0.f;
  const float* w2q = w2t + w * 16;      // uniform -> scalar loads
  #pragma unroll 4
  for (int kg = 0; kg < 32; ++kg) {
    unsigned u = pk[kg * 64 + l];
    #pragma unroll
    for (int kk = 0; kk < 4; ++kk) {
      const float* wr = w2q + (kg * 4 + kk) * 64;
      float h = (float)((u >> (8 * kk)) & 255u);
      #pragma unroll
      for (int j = 0; j < 16; ++j) acc2[j] = fmaf(h, wr[j], acc2[j]);
    }
  }

  // ---- LN2 + spike + mi ----
  float h2a[16];
  {
    const float* b2q = b2 + w * 16;
    float sm = 0.f;
    #pragma unroll
    for (int j = 0; j < 16; ++j) { h2a[j] = acc2[j] + b2q[j]; sm += h2a[j]; }
    red1[w][l] = sm;
  }
  __syncthreads();
  float mu2 = (red1[0][l] + red1[1][l] + red1[2][l] + red1[3][l]) * (1.0f / 64.0f);
  {
    float v = 0.f;
    #pragma unroll
    for (int j = 0; j < 16; ++j) { float d = h2a[j] - mu2; v = fmaf(d, d, v); }
    red2[w][l] = v;
  }
  __syncthreads();
  float var2 = (red2[0][l] + red2[1][l] + red2[2][l] + red2[3][l]) * (1.0f / 64.0f);
  float inv2 = 1.0f / sqrtf(var2 + 1e-5f);
  float mip = 0.f;
  {
    const float* g2q  = g2  + w * 16;
    const float* be2q = be2 + w * 16;
    const float* w3q  = w3  + w * 16;
    #pragma unroll
    for (int j = 0; j < 16; ++j) {
      float p = spikef((h2a[j] - mu2) * inv2 * g2q[j] + be2q[j]);
      mip = fmaf(p, w3q[j], mip);
    }
  }
  red1[w][l] = mip;    // safe: all red1 readers passed the red2 barrier
  __syncthreads();
  if (w == 0) {
    float mi = red1[0][l] + red1[1][l] + red1[2][l] + red1[3][l] + b3[0];
    mi_out[b * HW + s0 + l] = mi;
    miL[l] = mi;
    float mn = mi, mx = mi;
    #pragma unroll
    for (int off = 32; off; off >>= 1) {
      mn = fminf(mn, __shfl_xor(mn, off));
      mx = fmaxf(mx, __shfl_xor(mx, off));
    }
    if (l == 0) {
      unsigned kmn = fkey(mn), kmx = fkey(mx);
      volatile unsigned* vmm = (volatile unsigned*)mm;
      if (kmn < vmm[0]) atomicMin(&mm[0], kmn);
      if (kmx > vmm[1]) atomicMax(&mm[1], kmx);
    }
  }
  __syncthreads();

  // ---- pooling: pool[b][c] += sum_pos mi[pos]*fm[b][c][pos] ----
  const float miv = miL[l];
  #pragma unroll 4
  for (int ci = 0; ci < 64; ++ci) {
    int c = (w << 6) + ci;
    float v = fmp[(size_t)c * HW] * miv;
    #pragma unroll
    for (int off = 32; off; off >>= 1) v += __shfl_xor(v, off);
    if (l == 0) atomicAdd(&pool[b * 256 + c], v);
  }
}

// ---------------- Kernel 3: projection + LN + spike -> channel scale ----------------
__global__ __launch_bounds__(256) void scale_kernel(
    const float* __restrict__ pool, const float* __restrict__ pw,
    const float* __restrict__ pb, const float* __restrict__ pg,
    const float* __restrict__ pbeta, float* __restrict__ scale,
    const unsigned* __restrict__ mm, float* __restrict__ gpar)
{
  __shared__ float pl[256];
  __shared__ float xsh[256];
  __shared__ float rs[4], rs2[4];
  int b = blockIdx.x, t = threadIdx.x;
  pl[t] = pool[b*256 + t];
  __syncthreads();
  int w = t >> 6, l = t & 63;
  float p0 = pl[l], p1 = pl[l+64], p2 = pl[l+128], p3 = pl[l+192];
  for (int jj = 0; jj < 64; ++jj) {
    int j = w*64 + jj;
    const float* row = pw + j*256;
    float s = row[l]*p0 + row[l+64]*p1 + row[l+128]*p2 + row[l+192]*p3;
    #pragma unroll
    for (int off = 32; off; off >>= 1) s += __shfl_xor(s, off);
    if (l == 0) xsh[j] = s;
  }
  __syncthreads();
  float x = xsh[t] + pb[t];
  float s = x;
  #pragma unroll
  for (int off = 32; off; off >>= 1) s += __shfl_xor(s, off);
  if (l == 0) rs[w] = s;
  __syncthreads();
  float mu = (rs[0]+rs[1]+rs[2]+rs[3]) * (1.0f/256.0f);
  float d = x - mu;
  float s2 = d*d;
  #pragma unroll
  for (int off = 32; off; off >>= 1) s2 += __shfl_xor(s2, off);
  if (l == 0) rs2[w] = s2;
  __syncthreads();
  float var = (rs2[0]+rs2[1]+rs2[2]+rs2[3]) * (1.0f/256.0f);
  float v = d / sqrtf(var + 1e-5f) * pg[t] + pbeta[t];
  scale[b*256 + t] = spikef(v);
  if (b == 0 && t == 0) {
    float mn = funkey(mm[0]), mx = funkey(mm[1]);
    gpar[0] = mn;
    gpar[1] = mx - mn + 1e-6f;
  }
}

// ---------------- Kernel 4: fusion map + normalized mi map ----------------
// grid (257, 16): x<256 -> one (b,c) row of 784 float4; x==256 -> mi norm for b
__global__ __launch_bounds__(256) void fuse_kernel(
    const float4* __restrict__ fm4, const float* __restrict__ scale,
    const float4* __restrict__ mi4, const float* __restrict__ gpar,
    float4* __restrict__ out4, float4* __restrict__ mi4out)
{
  const int c = blockIdx.x, b = blockIdx.y, t = threadIdx.x;
  if (c < 256) {
    float s = scale[b * 256 + c];
    size_t base = ((size_t)b * 256 + c) * 784;
    #pragma unroll
    for (int i = 0; i < 3; ++i) {
      int idx = t + i * 256;
      float4 v = fm4[base + idx];
      out4[base + idx] = make_float4(v.x*s, v.y*s, v.z*s, v.w*s);
    }
    int idx = t + 768;
    if (idx < 784) {
      float4 v = fm4[base + idx];
      out4[base + idx] = make_float4(v.x*s, v.y*s, v.z*s, v.w*s);
    }
  } else {
    float gmin = gpar[0], den = gpar[1];
    size_t base = (size_t)b * 784;
    #pragma unroll
    for (int i = 0; i < 3; ++i) {
      int idx = t + i * 256;
      float4 v = mi4[base + idx];
      mi4out[base + idx] = make_float4((v.x-gmin)/den, (v.y-gmin)/den,
                                       (v.z-gmin)/den, (v.w-gmin)/den);
    }
    int idx = t + 768;
    if (idx < 784) {
      float4 v = mi4[base + idx];
      mi4out[base + idx] = make_float4((v.x-gmin)/den, (v.y-gmin)/den,
                                       (v.z-gmin)/den, (v.w-gmin)/den);
    }
  }
}

extern "C" void kernel_launch(void* const* d_in, const int* in_sizes, int n_in,
                              void* d_out, int out_size, void* d_ws, size_t ws_size,
                              hipStream_t stream)
{
  const float* fm    = (const float*)d_in[0];
  const float* audio = (const float*)d_in[1];
  const float* w1    = (const float*)d_in[2];
  const float* b1    = (const float*)d_in[3];
  const float* g1    = (const float*)d_in[4];
  const float* be1   = (const float*)d_in[5];
  const float* w2    = (const float*)d_in[6];
  const float* b2    = (const float*)d_in[7];
  const float* g2    = (const float*)d_in[8];
  const float* be2   = (const float*)d_in[9];
  const float* w3    = (const float*)d_in[10];
  const float* b3    = (const float*)d_in[11];
  const float* pw    = (const float*)d_in[12];
  const float* pb    = (const float*)d_in[13];
  const float* pg    = (const float*)d_in[14];
  const float* pbeta = (const float*)d_in[15];

  float* ws    = (float*)d_ws;
  float* a_pre = ws;               // 2048 floats
  float* pool  = ws + 2048;        // 4096
  float* scale = ws + 6144;        // 4096
  float* mi    = ws + 10240;       // 50176 (16B aligned)
  float* w1t   = ws + 60416;       // 32768  [c][j]
  float* w2t   = ws + 93184;       // 8192   [k][j2]
  unsigned* mm = (unsigned*)(ws + 101376);  // 2 keys
  float* gpar  = ws + 101378;      // gmin, denom

  float* out    = (float*)d_out;
  float* mi4out = out + NPOS;

  prep_kernel<<<177, 256, 0, stream>>>(audio, w1, b1, w2, a_pre, w1t, w2t,
                                       pool, mm);
  mlp_kernel<<<dim3(49, 16), 256, 0, stream>>>(fm, w1t, w2t, b2, w3, b3,
                                               g1, be1, g2, be2,
                                               a_pre, mi, pool, mm);
  scale_kernel<<<16, 256, 0, stream>>>(pool, pw, pb, pg, pbeta, scale, mm, gpar);
  fuse_kernel<<<dim3(257, 16), 256, 0, stream>>>((const float4*)fm, scale,
                                                 (const float4*)mi, gpar,
                                                 (float4*)out, (float4*)mi4out);
}

// Round 7
// 313.370 us; speedup vs baseline: 1.6002x; 1.6002x over previous
//
#include <hip/hip_runtime.h>

#define HW 3136
#define NPOS 12845056   // 16*256*3136
#define KC 32

__device__ __forceinline__ unsigned fkey(float f) {
  unsigned u = __float_as_uint(f);
  return (u & 0x80000000u) ? ~u : (u | 0x80000000u);
}
__device__ __forceinline__ float funkey(unsigned u) {
  return __uint_as_float((u & 0x80000000u) ? (u & 0x7FFFFFFFu) : ~u);
}
__device__ __forceinline__ float spikef(float x) {
  return fminf(fmaxf(rintf(x), 0.0f), 4.0f);
}

// ---------------- Kernel 1: transposes + audio pre-projection + init ----------------
__global__ __launch_bounds__(256) void prep_kernel(
    const float* __restrict__ audio, const float* __restrict__ w1,
    const float* __restrict__ b1, const float* __restrict__ w2,
    float* __restrict__ a_pre, float* __restrict__ w1t,
    float* __restrict__ w2t, float* __restrict__ pool,
    unsigned* __restrict__ mm)
{
  __shared__ float au[256];
  const int bx = blockIdx.x, t = threadIdx.x;
  if (bx < 128) {                       // w1 visual half -> w1t[c][j]
    int idx = bx * 256 + t;             // 32768
    int c = idx >> 7, j = idx & 127;
    w1t[idx] = w1[j * 512 + c];
  } else if (bx < 160) {                // w2 -> w2t[k][j2]
    int idx = (bx - 128) * 256 + t;     // 8192
    int k = idx >> 6, j2 = idx & 63;
    w2t[idx] = w2[j2 * 128 + k];
  } else if (bx < 176) {                // a_pre[b][j] = b1[j] + w1[j][256:512].audio[b]
    int b = bx - 160;
    au[t] = audio[b * 256 + t];
    __syncthreads();
    int w = t >> 6, l = t & 63;
    float a0 = au[l], a1 = au[l + 64], a2 = au[l + 128], a3 = au[l + 192];
    for (int jj = 0; jj < 32; ++jj) {
      int j = w * 32 + jj;
      const float* row = w1 + j * 512 + 256;
      float s = row[l] * a0 + row[l + 64] * a1 + row[l + 128] * a2 + row[l + 192] * a3;
      #pragma unroll
      for (int off = 32; off; off >>= 1) s += __shfl_xor(s, off);
      if (l == 0) a_pre[b * 128 + j] = s + b1[j];
    }
  } else {
    for (int i = t; i < 4096; i += 256) pool[i] = 0.0f;
    if (t == 0) { mm[0] = 0xFFFFFFFFu; mm[1] = 0u; }
  }
}

// ---------------- Kernel 2: fused MLP + mi + pooling ----------------
// 256 threads; block tile 64 pos x 128 j; thread tile 4 pos x 8 j (acc[4][8]).
// Both operands from LDS via ds_read_b128 (w: 4-unique broadcast, fm: 16-unique
// contiguous -> conflict-free). NO scalar loads in the hot loop (round-6 fix:
// kernel was scalar-pipe-bound). fm+w1 staged via global_load_lds, double-
// buffered KC=32 chunks. GEMM2 reads h1 floats from LDS (aliased over GEMM1
// buffers) + staged w2 chunks. 53.5 KB LDS -> 3 blocks/CU. Grid 49x16, no tail.
__global__ __launch_bounds__(256, 3) void mlp_kernel(
    const float* __restrict__ fm, const float* __restrict__ w1t,
    const float* __restrict__ w2t, const float* __restrict__ b2,
    const float* __restrict__ w3, const float* __restrict__ b3,
    const float* __restrict__ g1, const float* __restrict__ be1,
    const float* __restrict__ g2, const float* __restrict__ be2,
    const float* __restrict__ a_pre, float* __restrict__ mi_out,
    float* __restrict__ pool, unsigned* __restrict__ mm)
{
  __shared__ __align__(16) unsigned char smem[49152];
  __shared__ float red1[16][64];     // 4 KB reduction scratch
  __shared__ float miL[64];

  float* fmb = (float*)smem;                    // [2][KC][64]   16 KB GEMM1 fm
  float* wb1 = (float*)(smem + 16384);          // [2][KC][128]  32 KB GEMM1 w
  float* h1f = (float*)smem;                    // [128][64]     32 KB spiked h1 (aliased)
  float* w2b = (float*)(smem + 32768);          // [2][KC][64]   16 KB GEMM2 w (aliased)

  const int b  = blockIdx.y;
  const int s0 = blockIdx.x * 64;
  const int t  = threadIdx.x;
  const int l  = t & 63;
  const int w  = t >> 6;
  const int pg = t & 15;          // pos = pg*4 + pp
  const int jg = t >> 4;          // GEMM1: j = jg*8 + jj ; GEMM2: j = jg*4 + jj

  const float* fmblk = fm + (size_t)b * 256 * HW + s0;

  auto stage1 = [&](int ch, int bd) {
    const int r0 = w * 8;                        // wave-uniform row base
    #pragma unroll
    for (int q = 0; q < 2; ++q) {                // fm: 4 rows per issue
      int row = r0 + q * 4 + (l >> 4);
      const float* g = fmblk + (size_t)(ch * KC + row) * HW + (l & 15) * 4;
      float* d = fmb + (bd * KC + r0 + q * 4) * 64;
      __builtin_amdgcn_global_load_lds(
          (const __attribute__((address_space(1))) void*)g,
          (__attribute__((address_space(3))) void*)d, 16, 0, 0);
    }
    #pragma unroll
    for (int q = 0; q < 4; ++q) {                // w1: 2 rows per issue
      int row = r0 + q * 2 + (l >> 5);
      const float* g = w1t + (size_t)(ch * KC + row) * 128 + (l & 31) * 4;
      float* d = wb1 + (bd * KC + r0 + q * 2) * 128;
      __builtin_amdgcn_global_load_lds(
          (const __attribute__((address_space(1))) void*)g,
          (__attribute__((address_space(3))) void*)d, 16, 0, 0);
    }
  };
  auto stage2 = [&](int kc, int bd) {
    const int r0 = w * 8;
    #pragma unroll
    for (int q = 0; q < 2; ++q) {                // w2: 4 rows per issue
      int row = r0 + q * 4 + (l >> 4);
      const float* g = w2t + (size_t)(kc * KC + row) * 64 + (l & 15) * 4;
      float* d = w2b + (bd * KC + r0 + q * 4) * 64;
      __builtin_amdgcn_global_load_lds(
          (const __attribute__((address_space(1))) void*)g,
          (__attribute__((address_space(3))) void*)d, 16, 0, 0);
    }
  };

  // ---- GEMM1: acc[4 pos][8 j] over K=256 ----
  float acc[4][8];
  #pragma unroll
  for (int pp = 0; pp < 4; ++pp)
    #pragma unroll
    for (int jj = 0; jj < 8; ++jj) acc[pp][jj] = 0.f;

  stage1(0, 0);
  #pragma unroll 1
  for (int ch = 0; ch < 8; ++ch) {
    __syncthreads();
    if (ch < 7) stage1(ch + 1, (ch + 1) & 1);
    const float* fb = fmb + (ch & 1) * KC * 64;
    const float* wb = wb1 + (ch & 1) * KC * 128;
    #pragma unroll 4
    for (int k = 0; k < KC; ++k) {
      float4 xf = *(const float4*)(fb + k * 64 + pg * 4);
      float4 w0 = *(const float4*)(wb + k * 128 + jg * 8);
      float4 w1v = *(const float4*)(wb + k * 128 + jg * 8 + 4);
      float xs[4] = {xf.x, xf.y, xf.z, xf.w};
      float wv[8] = {w0.x, w0.y, w0.z, w0.w, w1v.x, w1v.y, w1v.z, w1v.w};
      #pragma unroll
      for (int pp = 0; pp < 4; ++pp)
        #pragma unroll
        for (int jj = 0; jj < 8; ++jj)
          acc[pp][jj] = fmaf(xs[pp], wv[jj], acc[pp][jj]);
    }
  }
  {
    float4 a0 = *(const float4*)(a_pre + b * 128 + jg * 8);
    float4 a1 = *(const float4*)(a_pre + b * 128 + jg * 8 + 4);
    float aw[8] = {a0.x, a0.y, a0.z, a0.w, a1.x, a1.y, a1.z, a1.w};
    #pragma unroll
    for (int pp = 0; pp < 4; ++pp)
      #pragma unroll
      for (int jj = 0; jj < 8; ++jj) acc[pp][jj] += aw[jj];
  }

  // ---- LN1 (two-pass) ----
  {
    float4 ps;
    float* p = &ps.x;
    #pragma unroll
    for (int pp = 0; pp < 4; ++pp) {
      float s = 0.f;
      #pragma unroll
      for (int jj = 0; jj < 8; ++jj) s += acc[pp][jj];
      p[pp] = s;
    }
    __syncthreads();               // prior red1 use: none first time (safe)
    *(float4*)&red1[jg][pg * 4] = ps;
  }
  __syncthreads();
  float mu[4];
  {
    float4 s = make_float4(0.f, 0.f, 0.f, 0.f);
    #pragma unroll
    for (int q = 0; q < 16; ++q) {
      float4 v = *(const float4*)&red1[q][pg * 4];
      s.x += v.x; s.y += v.y; s.z += v.z; s.w += v.w;
    }
    mu[0] = s.x * (1.0f/128.0f); mu[1] = s.y * (1.0f/128.0f);
    mu[2] = s.z * (1.0f/128.0f); mu[3] = s.w * (1.0f/128.0f);
  }
  __syncthreads();
  {
    float4 vs;
    float* p = &vs.x;
    #pragma unroll
    for (int pp = 0; pp < 4; ++pp) {
      float s = 0.f;
      #pragma unroll
      for (int jj = 0; jj < 8; ++jj) { float d = acc[pp][jj] - mu[pp]; s = fmaf(d, d, s); }
      p[pp] = s;
    }
    *(float4*)&red1[jg][pg * 4] = vs;
  }
  __syncthreads();
  float inv[4];
  {
    float4 s = make_float4(0.f, 0.f, 0.f, 0.f);
    #pragma unroll
    for (int q = 0; q < 16; ++q) {
      float4 v = *(const float4*)&red1[q][pg * 4];
      s.x += v.x; s.y += v.y; s.z += v.z; s.w += v.w;
    }
    inv[0] = 1.0f / sqrtf(s.x * (1.0f/128.0f) + 1e-5f);
    inv[1] = 1.0f / sqrtf(s.y * (1.0f/128.0f) + 1e-5f);
    inv[2] = 1.0f / sqrtf(s.z * (1.0f/128.0f) + 1e-5f);
    inv[3] = 1.0f / sqrtf(s.w * (1.0f/128.0f) + 1e-5f);
  }
  __syncthreads();                 // all GEMM1/red1 reads done before aliasing writes

  // ---- spike + write h1f [j][pos]; start staging w2 chunk 0 ----
  stage2(0, 0);
  {
    float4 g1a = *(const float4*)(g1 + jg * 8);
    float4 g1b = *(const float4*)(g1 + jg * 8 + 4);
    float4 ba  = *(const float4*)(be1 + jg * 8);
    float4 bb  = *(const float4*)(be1 + jg * 8 + 4);
    float gv[8] = {g1a.x, g1a.y, g1a.z, g1a.w, g1b.x, g1b.y, g1b.z, g1b.w};
    float bv[8] = {ba.x, ba.y, ba.z, ba.w, bb.x, bb.y, bb.z, bb.w};
    #pragma unroll
    for (int jj = 0; jj < 8; ++jj) {
      float4 hv;
      hv.x = spikef((acc[0][jj] - mu[0]) * inv[0] * gv[jj] + bv[jj]);
      hv.y = spikef((acc[1][jj] - mu[1]) * inv[1] * gv[jj] + bv[jj]);
      hv.z = spikef((acc[2][jj] - mu[2]) * inv[2] * gv[jj] + bv[jj]);
      hv.w = spikef((acc[3][jj] - mu[3]) * inv[3] * gv[jj] + bv[jj]);
      *(float4*)(h1f + (jg * 8 + jj) * 64 + pg * 4) = hv;
    }
  }
  __syncthreads();                 // h1f + w2 chunk 0 resident

  // ---- GEMM2: a2[4 pos][4 j] over K=128 ----
  float a2[4][4];
  #pragma unroll
  for (int pp = 0; pp < 4; ++pp)
    #pragma unroll
    for (int jj = 0; jj < 4; ++jj) a2[pp][jj] = 0.f;
  #pragma unroll 1
  for (int kc = 0; kc < 4; ++kc) {
    if (kc < 3) stage2(kc + 1, (kc + 1) & 1);
    const float* wb = w2b + (kc & 1) * KC * 64;
    #pragma unroll 4
    for (int k = 0; k < KC; ++k) {
      float4 hf = *(const float4*)(h1f + (kc * KC + k) * 64 + pg * 4);
      float4 wv4 = *(const float4*)(wb + k * 64 + jg * 4);
      float hs[4] = {hf.x, hf.y, hf.z, hf.w};
      float wv[4] = {wv4.x, wv4.y, wv4.z, wv4.w};
      #pragma unroll
      for (int pp = 0; pp < 4; ++pp)
        #pragma unroll
        for (int jj = 0; jj < 4; ++jj)
          a2[pp][jj] = fmaf(hs[pp], wv[jj], a2[pp][jj]);
    }
    __syncthreads();
  }

  // ---- LN2 + spike + mi ----
  float h2[4][4];
  {
    float4 b2v = *(const float4*)(b2 + jg * 4);
    float bb[4] = {b2v.x, b2v.y, b2v.z, b2v.w};
    float4 ps;
    float* p = &ps.x;
    #pragma unroll
    for (int pp = 0; pp < 4; ++pp) {
      float s = 0.f;
      #pragma unroll
      for (int jj = 0; jj < 4; ++jj) { h2[pp][jj] = a2[pp][jj] + bb[jj]; s += h2[pp][jj]; }
      p[pp] = s;
    }
    *(float4*)&red1[jg][pg * 4] = ps;
  }
  __syncthreads();
  float mu2[4];
  {
    float4 s = make_float4(0.f, 0.f, 0.f, 0.f);
    #pragma unroll
    for (int q = 0; q < 16; ++q) {
      float4 v = *(const float4*)&red1[q][pg * 4];
      s.x += v.x; s.y += v.y; s.z += v.z; s.w += v.w;
    }
    mu2[0] = s.x * (1.0f/64.0f); mu2[1] = s.y * (1.0f/64.0f);
    mu2[2] = s.z * (1.0f/64.0f); mu2[3] = s.w * (1.0f/64.0f);
  }
  __syncthreads();
  {
    float4 vs;
    float* p = &vs.x;
    #pragma unroll
    for (int pp = 0; pp < 4; ++pp) {
      float s = 0.f;
      #pragma unroll
      for (int jj = 0; jj < 4; ++jj) { float d = h2[pp][jj] - mu2[pp]; s = fmaf(d, d, s); }
      p[pp] = s;
    }
    *(float4*)&red1[jg][pg * 4] = vs;
  }
  __syncthreads();
  float inv2[4];
  {
    float4 s = make_float4(0.f, 0.f, 0.f, 0.f);
    #pragma unroll
    for (int q = 0; q < 16; ++q) {
      float4 v = *(const float4*)&red1[q][pg * 4];
      s.x += v.x; s.y += v.y; s.z += v.z; s.w += v.w;
    }
    inv2[0] = 1.0f / sqrtf(s.x * (1.0f/64.0f) + 1e-5f);
    inv2[1] = 1.0f / sqrtf(s.y * (1.0f/64.0f) + 1e-5f);
    inv2[2] = 1.0f / sqrtf(s.z * (1.0f/64.0f) + 1e-5f);
    inv2[3] = 1.0f / sqrtf(s.w * (1.0f/64.0f) + 1e-5f);
  }
  __syncthreads();
  {
    float4 g2v = *(const float4*)(g2 + jg * 4);
    float4 be2v = *(const float4*)(be2 + jg * 4);
    float4 w3v = *(const float4*)(w3 + jg * 4);
    float gv[4] = {g2v.x, g2v.y, g2v.z, g2v.w};
    float bv[4] = {be2v.x, be2v.y, be2v.z, be2v.w};
    float wv[4] = {w3v.x, w3v.y, w3v.z, w3v.w};
    float4 ps;
    float* p = &ps.x;
    #pragma unroll
    for (int pp = 0; pp < 4; ++pp) {
      float s = 0.f;
      #pragma unroll
      for (int jj = 0; jj < 4; ++jj) {
        float sp = spikef((h2[pp][jj] - mu2[pp]) * inv2[pp] * gv[jj] + bv[jj]);
        s = fmaf(sp, wv[jj], s);
      }
      p[pp] = s;
    }
    *(float4*)&red1[jg][pg * 4] = ps;
  }
  __syncthreads();
  if (t < 16) {                    // lanes 0..15 of wave 0, each owns 4 positions
    float4 s = make_float4(0.f, 0.f, 0.f, 0.f);
    #pragma unroll
    for (int q = 0; q < 16; ++q) {
      float4 v = *(const float4*)&red1[q][pg * 4];
      s.x += v.x; s.y += v.y; s.z += v.z; s.w += v.w;
    }
    float b3v = b3[0];
    float4 miv = make_float4(s.x + b3v, s.y + b3v, s.z + b3v, s.w + b3v);
    *(float4*)(mi_out + b * HW + s0 + pg * 4) = miv;
    *(float4*)(miL + pg * 4) = miv;
    float mn = fminf(fminf(miv.x, miv.y), fminf(miv.z, miv.w));
    float mx = fmaxf(fmaxf(miv.x, miv.y), fmaxf(miv.z, miv.w));
    #pragma unroll
    for (int off = 8; off; off >>= 1) {
      mn = fminf(mn, __shfl_xor(mn, off));
      mx = fmaxf(mx, __shfl_xor(mx, off));
    }
    if (t == 0) {
      unsigned kmn = fkey(mn), kmx = fkey(mx);
      volatile unsigned* vmm = (volatile unsigned*)mm;
      if (kmn < vmm[0]) atomicMin(&mm[0], kmn);
      if (kmx > vmm[1]) atomicMax(&mm[1], kmx);
    }
  }
  __syncthreads();

  // ---- pooling: pool[b][c] += sum_pos mi[pos]*fm[b][c][pos] ----
  const float miv = miL[l];
  const float* fmp = fmblk + l;
  #pragma unroll 4
  for (int ci = 0; ci < 64; ++ci) {
    int c = (w << 6) + ci;
    float v = fmp[(size_t)c * HW] * miv;
    #pragma unroll
    for (int off = 32; off; off >>= 1) v += __shfl_xor(v, off);
    if (l == 0) atomicAdd(&pool[b * 256 + c], v);
  }
}

// ---------------- Kernel 3: projection + LN + spike -> channel scale ----------------
__global__ __launch_bounds__(256) void scale_kernel(
    const float* __restrict__ pool, const float* __restrict__ pw,
    const float* __restrict__ pb, const float* __restrict__ pg,
    const float* __restrict__ pbeta, float* __restrict__ scale,
    const unsigned* __restrict__ mm, float* __restrict__ gpar)
{
  __shared__ float pl[256];
  __shared__ float xsh[256];
  __shared__ float rs[4], rs2[4];
  int b = blockIdx.x, t = threadIdx.x;
  pl[t] = pool[b*256 + t];
  __syncthreads();
  int w = t >> 6, l = t & 63;
  float p0 = pl[l], p1 = pl[l+64], p2 = pl[l+128], p3 = pl[l+192];
  for (int jj = 0; jj < 64; ++jj) {
    int j = w*64 + jj;
    const float* row = pw + j*256;
    float s = row[l]*p0 + row[l+64]*p1 + row[l+128]*p2 + row[l+192]*p3;
    #pragma unroll
    for (int off = 32; off; off >>= 1) s += __shfl_xor(s, off);
    if (l == 0) xsh[j] = s;
  }
  __syncthreads();
  float x = xsh[t] + pb[t];
  float s = x;
  #pragma unroll
  for (int off = 32; off; off >>= 1) s += __shfl_xor(s, off);
  if (l == 0) rs[w] = s;
  __syncthreads();
  float mu = (rs[0]+rs[1]+rs[2]+rs[3]) * (1.0f/256.0f);
  float d = x - mu;
  float s2 = d*d;
  #pragma unroll
  for (int off = 32; off; off >>= 1) s2 += __shfl_xor(s2, off);
  if (l == 0) rs2[w] = s2;
  __syncthreads();
  float var = (rs2[0]+rs2[1]+rs2[2]+rs2[3]) * (1.0f/256.0f);
  float v = d / sqrtf(var + 1e-5f) * pg[t] + pbeta[t];
  scale[b*256 + t] = spikef(v);
  if (b == 0 && t == 0) {
    float mn = funkey(mm[0]), mx = funkey(mm[1]);
    gpar[0] = mn;
    gpar[1] = mx - mn + 1e-6f;
  }
}

// ---------------- Kernel 4: fusion map + normalized mi map ----------------
__global__ __launch_bounds__(256) void fuse_kernel(
    const float4* __restrict__ fm4, const float* __restrict__ scale,
    const float4* __restrict__ mi4, const float* __restrict__ gpar,
    float4* __restrict__ out4, float4* __restrict__ mi4out)
{
  const int c = blockIdx.x, b = blockIdx.y, t = threadIdx.x;
  if (c < 256) {
    float s = scale[b * 256 + c];
    size_t base = ((size_t)b * 256 + c) * 784;
    #pragma unroll
    for (int i = 0; i < 3; ++i) {
      int idx = t + i * 256;
      float4 v = fm4[base + idx];
      out4[base + idx] = make_float4(v.x*s, v.y*s, v.z*s, v.w*s);
    }
    int idx = t + 768;
    if (idx < 784) {
      float4 v = fm4[base + idx];
      out4[base + idx] = make_float4(v.x*s, v.y*s, v.z*s, v.w*s);
    }
  } else {
    float gmin = gpar[0], den = gpar[1];
    size_t base = (size_t)b * 784;
    #pragma unroll
    for (int i = 0; i < 3; ++i) {
      int idx = t + i * 256;
      float4 v = mi4[base + idx];
      mi4out[base + idx] = make_float4((v.x-gmin)/den, (v.y-gmin)/den,
                                       (v.z-gmin)/den, (v.w-gmin)/den);
    }
    int idx = t + 768;
    if (idx < 784) {
      float4 v = mi4[base + idx];
      mi4out[base + idx] = make_float4((v.x-gmin)/den, (v.y-gmin)/den,
                                       (v.z-gmin)/den, (v.w-gmin)/den);
    }
  }
}

extern "C" void kernel_launch(void* const* d_in, const int* in_sizes, int n_in,
                              void* d_out, int out_size, void* d_ws, size_t ws_size,
                              hipStream_t stream)
{
  const float* fm    = (const float*)d_in[0];
  const float* audio = (const float*)d_in[1];
  const float* w1    = (const float*)d_in[2];
  const float* b1    = (const float*)d_in[3];
  const float* g1    = (const float*)d_in[4];
  const float* be1   = (const float*)d_in[5];
  const float* w2    = (const float*)d_in[6];
  const float* b2    = (const float*)d_in[7];
  const float* g2    = (const float*)d_in[8];
  const float* be2   = (const float*)d_in[9];
  const float* w3    = (const float*)d_in[10];
  const float* b3    = (const float*)d_in[11];
  const float* pw    = (const float*)d_in[12];
  const float* pb    = (const float*)d_in[13];
  const float* pg    = (const float*)d_in[14];
  const float* pbeta = (const float*)d_in[15];

  float* ws    = (float*)d_ws;
  float* a_pre = ws;               // 2048 floats
  float* pool  = ws + 2048;        // 4096
  float* scale = ws + 6144;        // 4096
  float* mi    = ws + 10240;       // 50176 (16B aligned)
  float* w1t   = ws + 60416;       // 32768  [c][j]
  float* w2t   = ws + 93184;       // 8192   [k][j2]
  unsigned* mm = (unsigned*)(ws + 101376);  // 2 keys
  float* gpar  = ws + 101378;      // gmin, denom

  float* out    = (float*)d_out;
  float* mi4out = out + NPOS;

  prep_kernel<<<177, 256, 0, stream>>>(audio, w1, b1, w2, a_pre, w1t, w2t,
                                       pool, mm);
  mlp_kernel<<<dim3(49, 16), 256, 0, stream>>>(fm, w1t, w2t, b2, w3, b3,
                                               g1, be1, g2, be2,
                                               a_pre, mi, pool, mm);
  scale_kernel<<<16, 256, 0, stream>>>(pool, pw, pb, pg, pbeta, scale, mm, gpar);
  fuse_kernel<<<dim3(257, 16), 256, 0, stream>>>((const float4*)fm, scale,
                                                 (const float4*)mi, gpar,
                                                 (float4*)out, (float4*)mi4out);
}